// Round 11
// baseline (2546.215 us; speedup 1.0000x reference)
//
#include <hip/hip_runtime.h>
#include <hip/hip_bf16.h>
#include <math.h>

#define B_  4
#define D_  1024
#define T_  512
#define V_  32000
#define CD_ 4096
#define NR  (B_*T_)          // 2048 rows
#define VT2 (V_/256)         // 125 v-tiles (256-wide)
#define NTILE1 ((V_/256)*(D_/256))   // 500 gemm1 tiles
#define NQ4 (VT2*4)          // 500 64-wide quarters
#define NC8 8

typedef __attribute__((ext_vector_type(8))) short short8v;  // 8 bf16 (4 VGPR)
typedef __attribute__((ext_vector_type(4))) float f32x4;    // MFMA acc

#define MFMA16(a,b,c) __builtin_amdgcn_mfma_f32_16x16x32_bf16((a),(b),(c),0,0,0)

#define ASM_VMCNT8() asm volatile("s_waitcnt vmcnt(8)" ::: "memory")
#define ASM_VMCNT4() asm volatile("s_waitcnt vmcnt(4)" ::: "memory")
#define ASM_VMCNT0() asm volatile("s_waitcnt vmcnt(0)" ::: "memory")
#define ASM_LGKM0()  asm volatile("s_waitcnt lgkmcnt(0)" ::: "memory")
#define SCHED_BAR()  __builtin_amdgcn_sched_barrier(0)

__device__ __forceinline__ unsigned short f2bf(float f) {
    return __builtin_bit_cast(unsigned short, __float2bfloat16(f));  // RNE
}
__device__ __forceinline__ float bf2f(unsigned short u) {
    unsigned int v = ((unsigned int)u) << 16;
    return __builtin_bit_cast(float, v);
}
__device__ __forceinline__ void glds16(const unsigned short* g, unsigned short* l) {
    __builtin_amdgcn_global_load_lds(
        (const __attribute__((address_space(1))) unsigned int*)g,
        (__attribute__((address_space(3))) unsigned int*)l, 16, 0, 0);
}
__device__ __forceinline__ void cvt8(const float4& x, const float4& y,
                                     short8v& h, short8v& l) {
    float xs[8] = {x.x, x.y, x.z, x.w, y.x, y.y, y.z, y.w};
    #pragma unroll
    for (int e = 0; e < 8; ++e) {
        unsigned short hb = f2bf(xs[e]);
        h[e] = (short)hb;
        l[e] = (short)f2bf(xs[e] - bf2f(hb));
    }
}
// bijective XCD swizzle (m204 form)
__device__ __forceinline__ int xcd_swz(int wg, int nwg) {
    int q = nwg >> 3, r = nwg & 7;
    int x = wg & 7, o = wg >> 3;
    return (x < r ? x * (q + 1) : r * (q + 1) + (x - r) * q) + o;
}
__device__ __forceinline__ void top2_ins(float& v1, int& i1, float& v2, int& i2,
                                         float nv, int ni) {
    if (nv > v1 || (nv == v1 && ni < i1)) { v2 = v1; i2 = i1; v1 = nv; i1 = ni; }
    else if (nv > v2 || (nv == v2 && ni < i2)) { v2 = nv; i2 = ni; }
}

// ---------------------------------------------------------------------------
// f32 -> hi/lo bf16 planes (Ootomo split, RNE both)
// ---------------------------------------------------------------------------
__global__ __launch_bounds__(256) void vq_cvt(const float* __restrict__ x,
                                              unsigned short* __restrict__ hi,
                                              unsigned short* __restrict__ lo,
                                              size_t n4) {
    size_t stride = (size_t)gridDim.x * 256;
    for (size_t i = (size_t)blockIdx.x * 256 + threadIdx.x; i < n4; i += stride) {
        float4 v = *(const float4*)(x + 4 * i);
        float xs[4] = {v.x, v.y, v.z, v.w};
        ushort4 h, l;
        unsigned short* hp = (unsigned short*)&h;
        unsigned short* lp = (unsigned short*)&l;
        #pragma unroll
        for (int e = 0; e < 4; ++e) {
            hp[e] = f2bf(xs[e]);
            lp[e] = f2bf(xs[e] - bf2f(hp[e]));
        }
        *(ushort4*)(hi + 4 * i) = h;
        *(ushort4*)(lo + 4 * i) = l;
    }
}

// ===========================================================================
// GEMM1 (R7-proven 897us): 8-phase 3-pass split-bf16, 256x256, BK=32.
// At its LDS-read-bandwidth roofline (24 ds_read_b128/wave-step -> 40% cap).
// ===========================================================================
#define T8_PHASE(pp, EXTRA)                                                   \
    {                                                                         \
        short8v aAh = *(const short8v*)&smem[cur][0][(wr8 + 2*(pp)) * 512 + lane8];     \
        short8v aAl = *(const short8v*)&smem[cur][1][(wr8 + 2*(pp)) * 512 + lane8];     \
        short8v aBh = *(const short8v*)&smem[cur][0][(wr8 + 2*(pp) + 1) * 512 + lane8]; \
        short8v aBl = *(const short8v*)&smem[cur][1][(wr8 + 2*(pp) + 1) * 512 + lane8]; \
        EXTRA;                                                                \
        SCHED_BAR();                                                          \
        __builtin_amdgcn_s_barrier();                                         \
        ASM_LGKM0();                                                          \
        SCHED_BAR();                                                          \
        __builtin_amdgcn_s_setprio(1);                                        \
        _Pragma("unroll")                                                     \
        for (int nf = 0; nf < 4; ++nf) {                                      \
            acc[2*(pp)][nf]   = MFMA16(aAh, bh[nf], acc[2*(pp)][nf]);         \
            acc[2*(pp)][nf]   = MFMA16(aAh, bl[nf], acc[2*(pp)][nf]);         \
            acc[2*(pp)][nf]   = MFMA16(aAl, bh[nf], acc[2*(pp)][nf]);         \
            acc[2*(pp)+1][nf] = MFMA16(aBh, bh[nf], acc[2*(pp)+1][nf]);       \
            acc[2*(pp)+1][nf] = MFMA16(aBh, bl[nf], acc[2*(pp)+1][nf]);       \
            acc[2*(pp)+1][nf] = MFMA16(aBl, bh[nf], acc[2*(pp)+1][nf]);       \
        }                                                                     \
        __builtin_amdgcn_s_setprio(0);                                        \
        __builtin_amdgcn_s_barrier();                                         \
        SCHED_BAR();                                                          \
    }

__global__ __launch_bounds__(512, 2) void vq_gemm1_t8(
    const unsigned short* __restrict__ Ahp, const unsigned short* __restrict__ Alp,
    const unsigned short* __restrict__ Bhp, const unsigned short* __restrict__ Blp,
    const float* __restrict__ bias,
    unsigned short* __restrict__ Phi, unsigned short* __restrict__ Plo)
{
    __shared__ unsigned short smem[2][4][8192];   // 128 KiB
    const int wg = xcd_swz(blockIdx.x, NTILE1);
    const int mt = (wg >> 2) * 256;   // V
    const int nt = (wg & 3) * 256;    // D
    const int lane = threadIdx.x & 63, w = threadIdx.x >> 6;
    const int wr = w >> 2, wc = w & 3;
    const int r16 = lane & 15, kg = lane >> 4;
    const int lane8 = lane * 8, wr8 = wr * 8, wc4 = wc * 4;
    const int pw = w >> 1;
    const unsigned short* gplane = (pw == 0) ? Ahp : (pw == 1) ? Alp
                                   : (pw == 2) ? Bhp : Blp;
    const int baseRow = (pw < 2 ? mt : nt) + (w & 1) * 128 + r16;
    const unsigned short* gsrc = gplane + (size_t)baseRow * CD_ + kg * 8;
    unsigned short* lb0 = &smem[0][pw][(w & 1) * 4096 + lane8];
    unsigned short* lb1 = &smem[1][pw][(w & 1) * 4096 + lane8];

    f32x4 acc[8][4];
    #pragma unroll
    for (int i = 0; i < 8; ++i)
        #pragma unroll
        for (int j = 0; j < 4; ++j) acc[i][j] = (f32x4){0.f, 0.f, 0.f, 0.f};

    #pragma unroll
    for (int q = 0; q < 8; ++q)
        glds16(gsrc + (size_t)q * 16 * CD_, lb0 + q * 512);
    ASM_VMCNT0();
    __builtin_amdgcn_s_barrier();
    SCHED_BAR();
    const int NT = CD_ / 32;
    for (int t = 0; t < NT; ++t) {
        const int cur = t & 1;
        unsigned short* lbN = cur ? lb0 : lb1;
        short8v bh[4], bl[4];
        #pragma unroll
        for (int nf = 0; nf < 4; ++nf) {
            bh[nf] = *(const short8v*)&smem[cur][2][(wc4 + nf) * 512 + lane8];
            bl[nf] = *(const short8v*)&smem[cur][3][(wc4 + nf) * 512 + lane8];
        }
        T8_PHASE(0,
            if (t + 1 < NT) {
                const size_t kof = (size_t)(t + 1) * 32;
                _Pragma("unroll")
                for (int q = 0; q < 8; ++q)
                    glds16(gsrc + kof + (size_t)q * 16 * CD_, lbN + q * 512);
            })
        T8_PHASE(1, (void)0)
        T8_PHASE(2, (void)0)
        T8_PHASE(3, if (t + 1 < NT) { ASM_VMCNT0(); })
    }

    // epilogue: +bias, split to hi/lo planes.  C/D: col=lane&15, row=kg*4+r
    #pragma unroll
    for (int nf = 0; nf < 4; ++nf) {
        const int col = nt + wc * 64 + nf * 16 + r16;
        const float bv = bias[col];
        #pragma unroll
        for (int mf = 0; mf < 8; ++mf) {
            const int rbase = mt + wr * 128 + mf * 16 + kg * 4;
            #pragma unroll
            for (int r = 0; r < 4; ++r) {
                float vv = acc[mf][nf][r] + bv;
                unsigned short h = f2bf(vv);
                unsigned short l = f2bf(vv - bf2f(h));
                size_t o = (size_t)(rbase + r) * D_ + col;
                Phi[o] = h; Plo[o] = l;
            }
        }
    }
}

// ===========================================================================
// GEMM2 coarse 1-pass: clone of the proven v2 loop (straight-line staging,
// NO pointer arrays), hi planes only. 256x256, BK=32, 8 waves, 64 KiB LDS
// -> 2 blocks/CU. Per-(row, 64-col-quarter) top-2 partials. Exact f64
// rescore of global top-8 follows (coarse err ~0.5% << top-8 gap ~30%).
// ===========================================================================
__global__ __launch_bounds__(512, 2) void vq_gemm2_c1(
    const unsigned short* __restrict__ Eh, const unsigned short* __restrict__ Ph,
    const float* __restrict__ ninv,
    float* __restrict__ parrv, int* __restrict__ parri)
{
    __shared__ unsigned short smem[2][2][8192];   // 64 KiB
    const int wg = xcd_swz(blockIdx.x, (NR/256) * VT2);
    const int nid = wg >> 3;          // 0..124 V-tile
    const int mt = (wg & 7) * 256;    // rows
    const int nt = nid * 256;         // V
    const int lane = threadIdx.x & 63, w = threadIdx.x >> 6;
    const int wr = w >> 2, wc = w & 3;
    const int r16 = lane & 15, kg = lane >> 4;
    const int lane8 = lane * 8, wr8 = wr * 8, wc4 = wc * 4;
    // staging: plane pw = w>>2 (0=E rows mt.., 1=P rows nt..), subtiles (w&3)*4+j
    const int pw = w >> 2;
    const int sq = (w & 3) * 4;
    const unsigned short* gp = pw ? Ph : Eh;
    const int baseRow = (pw ? nt : mt) + sq * 16 + r16;
    const unsigned short* gsrc = gp + (size_t)baseRow * D_ + kg * 8;
    unsigned short* lb0 = &smem[0][pw][sq * 512 + lane8];
    unsigned short* lb1 = &smem[1][pw][sq * 512 + lane8];

    f32x4 acc[8][4];
    #pragma unroll
    for (int i = 0; i < 8; ++i)
        #pragma unroll
        for (int j = 0; j < 4; ++j) acc[i][j] = (f32x4){0.f, 0.f, 0.f, 0.f};

    #pragma unroll
    for (int q = 0; q < 4; ++q)
        glds16(gsrc + (size_t)q * 16 * D_, lb0 + q * 512);
    ASM_VMCNT0();
    __builtin_amdgcn_s_barrier();
    SCHED_BAR();

    const int NT = D_ / 32;   // 32
    for (int t = 0; t < NT; ++t) {
        const int cur = t & 1;
        if (t + 1 < NT) {
            unsigned short* lb = cur ? lb0 : lb1;
            const size_t kof = (size_t)(t + 1) * 32;
            #pragma unroll
            for (int q = 0; q < 4; ++q)
                glds16(gsrc + kof + (size_t)q * 16 * D_, lb + q * 512);
            ASM_VMCNT4();          // prev step's 4 landed; 4 new in flight
        } else {
            ASM_VMCNT0();
        }
        __builtin_amdgcn_s_barrier();
        SCHED_BAR();
        short8v bfr[4];
        #pragma unroll
        for (int nf = 0; nf < 4; ++nf)
            bfr[nf] = *(const short8v*)&smem[cur][1][(wc4 + nf) * 512 + lane8];
        #pragma unroll
        for (int g = 0; g < 4; ++g) {
            short8v a0 = *(const short8v*)&smem[cur][0][(wr8 + 2*g) * 512 + lane8];
            short8v a1 = *(const short8v*)&smem[cur][0][(wr8 + 2*g + 1) * 512 + lane8];
            __builtin_amdgcn_s_setprio(1);
            #pragma unroll
            for (int nf = 0; nf < 4; ++nf) {
                acc[2*g][nf]   = MFMA16(a0, bfr[nf], acc[2*g][nf]);
                acc[2*g+1][nf] = MFMA16(a1, bfr[nf], acc[2*g+1][nf]);
            }
            __builtin_amdgcn_s_setprio(0);
        }
        ASM_LGKM0();
        __builtin_amdgcn_s_barrier();
        SCHED_BAR();
    }

    // per-(row, quarter) top-2; ties -> smallest v
    const int qid = nid * 4 + wc;     // 0..499
    float nv[4];
    #pragma unroll
    for (int nf = 0; nf < 4; ++nf) nv[nf] = ninv[nt + wc * 64 + nf * 16 + r16];
    #pragma unroll
    for (int mf = 0; mf < 8; ++mf) {
        #pragma unroll
        for (int r = 0; r < 4; ++r) {
            float v1 = -INFINITY, v2 = -INFINITY;
            int i1 = 0x7fffffff, i2 = 0x7fffffff;
            #pragma unroll
            for (int nf = 0; nf < 4; ++nf) {
                float s = acc[mf][nf][r] * nv[nf];
                int ci = nt + wc * 64 + nf * 16 + r16;
                top2_ins(v1, i1, v2, i2, s, ci);
            }
            #pragma unroll
            for (int m = 8; m >= 1; m >>= 1) {
                float ov1 = __shfl_xor(v1, m, 16); int oi1 = __shfl_xor(i1, m, 16);
                float ov2 = __shfl_xor(v2, m, 16); int oi2 = __shfl_xor(i2, m, 16);
                top2_ins(v1, i1, v2, i2, ov1, oi1);
                top2_ins(v1, i1, v2, i2, ov2, oi2);
            }
            if (r16 == 0) {
                const int row = mt + wr * 128 + mf * 16 + kg * 4 + r;
                size_t off = (size_t)row * (NQ4 * 2) + qid * 2;
                parrv[off] = v1;     parri[off] = i1;
                parrv[off + 1] = v2; parri[off + 1] = i2;
            }
        }
    }
}

// ---------------------------------------------------------------------------
// per-row global top-8 of the 1000 quarter partials (1 thread/row,
// static compare-swap cascade -> no scratch)
// ---------------------------------------------------------------------------
__global__ __launch_bounds__(256) void vq_top8(const float* __restrict__ parrv,
                                               const int* __restrict__ parri,
                                               int* __restrict__ cand) {
    const int i = blockIdx.x * 256 + threadIdx.x;
    if (i >= NR) return;
    float v[NC8]; int id[NC8];
    #pragma unroll
    for (int k = 0; k < NC8; ++k) { v[k] = -INFINITY; id[k] = 0x7fffffff; }
    const float* pv = parrv + (size_t)i * (NQ4 * 2);
    const int*   pi = parri + (size_t)i * (NQ4 * 2);
    for (int j = 0; j < NQ4 * 2; ++j) {
        float nv = pv[j];
        int   ni = pi[j];
        #pragma unroll
        for (int k = 0; k < NC8; ++k) {
            bool better = (nv > v[k]) || (nv == v[k] && ni < id[k]);
            float tv = v[k]; int ti = id[k];
            if (better) { v[k] = nv; id[k] = ni; nv = tv; ni = ti; }
        }
    }
    #pragma unroll
    for (int k = 0; k < NC8; ++k) cand[i * NC8 + k] = id[k];
}

// ---------------------------------------------------------------------------
// exact f64 rescore of the 8 candidates -> final index (deterministic)
// ---------------------------------------------------------------------------
__global__ __launch_bounds__(256) void vq_rescore8(
    const unsigned short* __restrict__ eh, const unsigned short* __restrict__ el,
    const unsigned short* __restrict__ ph, const unsigned short* __restrict__ pl,
    const float* __restrict__ ninv, const int* __restrict__ cand,
    int* __restrict__ idxw, float* __restrict__ outI) {
    __shared__ float e[D_];
    __shared__ double wsum[NC8][4];
    const int row = blockIdx.x;
    const int tid = threadIdx.x, lane = tid & 63, wv = tid >> 6;
    {
        ushort4 h = *(const ushort4*)(eh + (size_t)row * D_ + tid * 4);
        ushort4 l = *(const ushort4*)(el + (size_t)row * D_ + tid * 4);
        const unsigned short* hp = (const unsigned short*)&h;
        const unsigned short* lp = (const unsigned short*)&l;
        #pragma unroll
        for (int j = 0; j < 4; ++j)
            e[tid * 4 + j] = bf2f(hp[j]) + bf2f(lp[j]);
    }
    __syncthreads();
    for (int c = 0; c < NC8; ++c) {
        int cv = cand[row * NC8 + c];
        ushort4 h = *(const ushort4*)(ph + (size_t)cv * D_ + tid * 4);
        ushort4 l = *(const ushort4*)(pl + (size_t)cv * D_ + tid * 4);
        const unsigned short* hp = (const unsigned short*)&h;
        const unsigned short* lp = (const unsigned short*)&l;
        double s = 0.0;
        #pragma unroll
        for (int j = 0; j < 4; ++j)
            s += (double)e[tid * 4 + j] * (double)(bf2f(hp[j]) + bf2f(lp[j]));
        #pragma unroll
        for (int off = 32; off >= 1; off >>= 1) s += __shfl_down(s, off);
        if (lane == 0) wsum[c][wv] = s;
    }
    __syncthreads();
    if (tid == 0) {
        double best = -1.0e300; int bi = 0x7fffffff;
        for (int c = 0; c < NC8; ++c) {
            int cv = cand[row * NC8 + c];
            double s = (wsum[c][0] + wsum[c][1] + wsum[c][2] + wsum[c][3])
                       * (double)ninv[cv];
            if (s > best || (s == best && cv < bi)) { best = s; bi = cv; }
        }
        idxw[row] = bi;
        outI[row] = (float)bi;
    }
}

// ---------------------------------------------------------------------------
__global__ __launch_bounds__(256) void vq_norms_pl(const unsigned short* __restrict__ ph,
                                                   const unsigned short* __restrict__ pl,
                                                   float* __restrict__ ninv) {
    const int row  = blockIdx.x * 4 + (threadIdx.x >> 6);
    const int lane = threadIdx.x & 63;
    float s = 0.f;
    #pragma unroll
    for (int q = 0; q < 2; ++q) {
        size_t o = (size_t)row * D_ + q * 512 + lane * 8;
        short8v h = *(const short8v*)(ph + o);
        short8v l = *(const short8v*)(pl + o);
        #pragma unroll
        for (int e = 0; e < 8; ++e) {
            float x = bf2f((unsigned short)h[e]) + bf2f((unsigned short)l[e]);
            s += x * x;
        }
    }
    #pragma unroll
    for (int off = 32; off >= 1; off >>= 1) s += __shfl_down(s, off);
    if (lane == 0) ninv[row] = 1.0f / fmaxf(sqrtf(s), 1e-12f);
}

__global__ __launch_bounds__(256) void vq_transpose_cvt(const float* __restrict__ z,
                                                        unsigned short* __restrict__ ehi,
                                                        unsigned short* __restrict__ elo) {
    __shared__ float tile[64][65];
    const int b = blockIdx.z, t0 = blockIdx.x * 64, d0 = blockIdx.y * 64;
    const int lane = threadIdx.x & 63, sub = threadIdx.x >> 6;
    for (int dd = sub; dd < 64; dd += 4)
        tile[dd][lane] = z[((size_t)b * D_ + d0 + dd) * T_ + t0 + lane];
    __syncthreads();
    for (int tt = sub; tt < 64; tt += 4) {
        float v = tile[lane][tt];
        unsigned short h = f2bf(v);
        unsigned short l = f2bf(v - bf2f(h));
        size_t o = (size_t)(b * T_ + t0 + tt) * D_ + d0 + lane;
        ehi[o] = h; elo[o] = l;
    }
}

__global__ __launch_bounds__(256) void vq_gather_pl(const unsigned short* __restrict__ ph,
                                                    const unsigned short* __restrict__ pl,
                                                    const int* __restrict__ idxw,
                                                    const float* __restrict__ z,
                                                    float* __restrict__ out0,
                                                    float* __restrict__ lpart) {
    __shared__ float zq[64][65];
    __shared__ int idx_s[64];
    __shared__ float wsum[4];
    const int b = blockIdx.z, t0 = blockIdx.x * 64, d0 = blockIdx.y * 64;
    const int tid = threadIdx.x;
    const int lane = tid & 63, sub = tid >> 6;
    if (tid < 64) idx_s[tid] = idxw[b * T_ + t0 + tid];
    __syncthreads();
    for (int tt = sub; tt < 64; tt += 4) {
        size_t o = (size_t)idx_s[tt] * D_ + d0 + lane;
        zq[tt][lane] = bf2f(ph[o]) + bf2f(pl[o]);
    }
    __syncthreads();
    float lacc = 0.f;
    for (int dd = sub; dd < 64; dd += 4) {
        const size_t base = ((size_t)b * D_ + d0 + dd) * T_ + t0 + lane;
        float q = zq[lane][dd];
        float zv = z[base];
        out0[base] = q;
        float dv = zv - q;
        lacc += dv * dv;
    }
    #pragma unroll
    for (int off = 32; off >= 1; off >>= 1) lacc += __shfl_down(lacc, off);
    if (lane == 0) wsum[sub] = lacc;
    __syncthreads();
    if (tid == 0)
        lpart[(blockIdx.z * 16 + blockIdx.y) * 8 + blockIdx.x] =
            wsum[0] + wsum[1] + wsum[2] + wsum[3];
}

__global__ void vq_loss(const float* __restrict__ lpart, float* __restrict__ outL) {
    const int b = threadIdx.x;
    if (b >= B_) return;
    float s = 0.f;
    for (int q = 0; q < 128; q++) s += lpart[b * 128 + q];
    s /= (float)(D_ * T_);
    outL[b]      = s;
    outL[B_ + b] = s;
}

// ===========================================================================
extern "C" void kernel_launch(void* const* d_in, const int* in_sizes, int n_in,
                              void* d_out, int out_size, void* d_ws, size_t ws_size,
                              hipStream_t stream) {
    const float* z        = (const float*)d_in[0];   // [B, D, T]
    const float* codebook = (const float*)d_in[1];   // [V, CD]
    const float* cb_w     = (const float*)d_in[2];   // [D, CD]
    const float* cb_b     = (const float*)d_in[3];   // [D]

    float* out0 = (float*)d_out;
    float* outI = out0 + (size_t)B_*D_*T_;
    float* outL = outI + NR;

    char* p = (char*)d_ws;
    auto alloc = [&](size_t bytes) { char* r = p; p += (bytes + 255) & ~(size_t)255; return r; };
    unsigned short* w_hi = (unsigned short*)alloc((size_t)D_ * CD_ * 2);
    unsigned short* w_lo = (unsigned short*)alloc((size_t)D_ * CD_ * 2);
    unsigned short* p_hi = (unsigned short*)alloc((size_t)V_ * D_ * 2);
    unsigned short* p_lo = (unsigned short*)alloc((size_t)V_ * D_ * 2);
    unsigned short* e_hi = (unsigned short*)alloc((size_t)NR * D_ * 2);
    unsigned short* e_lo = (unsigned short*)alloc((size_t)NR * D_ * 2);
    float* ninv  = (float*)alloc((size_t)V_ * 4);
    float* parrv = (float*)alloc((size_t)NR * NQ4 * 2 * 4);   // 16 MB
    int*   parri = (int*)  alloc((size_t)NR * NQ4 * 2 * 4);   // 16 MB
    int*   cand  = (int*)  alloc((size_t)NR * NC8 * 4);
    int*   idxw  = (int*)  alloc((size_t)NR * 4);
    float* lpart = (float*)alloc((size_t)2048 * 4);
    unsigned short* c_hi = (unsigned short*)alloc((size_t)V_ * CD_ * 2);
    unsigned short* c_lo = (unsigned short*)alloc((size_t)V_ * CD_ * 2);
    // ~720 MB total; R10 proved >= 1.21 GB available

    vq_cvt<<<512, 256, 0, stream>>>(cb_w, w_hi, w_lo, (size_t)D_ * CD_ / 4);
    vq_transpose_cvt<<<dim3(T_/64, D_/64, B_), 256, 0, stream>>>(z, e_hi, e_lo);
    vq_cvt<<<4096, 256, 0, stream>>>(codebook, c_hi, c_lo, (size_t)V_ * CD_ / 4);

    vq_gemm1_t8<<<NTILE1, 512, 0, stream>>>(c_hi, c_lo, w_hi, w_lo,
                                            cb_b, p_hi, p_lo);
    vq_norms_pl<<<V_/4, 256, 0, stream>>>(p_hi, p_lo, ninv);
    vq_gemm2_c1<<<(NR/256) * VT2, 512, 0, stream>>>(e_hi, p_hi, ninv, parrv, parri);
    vq_top8<<<NR/256, 256, 0, stream>>>(parrv, parri, cand);
    vq_rescore8<<<NR, 256, 0, stream>>>(e_hi, e_lo, p_hi, p_lo, ninv, cand,
                                        idxw, outI);
    vq_gather_pl<<<dim3(T_/64, D_/64, B_), 256, 0, stream>>>(p_hi, p_lo, idxw, z,
                                                             out0, lpart);
    vq_loss<<<1, 64, 0, stream>>>(lpart, outL);
}

// Round 12
// 1865.385 us; speedup vs baseline: 1.3650x; 1.3650x over previous
//
#include <hip/hip_runtime.h>
#include <hip/hip_bf16.h>
#include <math.h>

#define B_  4
#define D_  1024
#define T_  512
#define V_  32000
#define CD_ 4096
#define NR  (B_*T_)          // 2048 rows
#define VT2 (V_/256)         // 125 v-tiles (256-wide)
#define NTILE1 ((V_/256)*(D_/256))   // 500 gemm1 tiles
#define NQ4 (VT2*4)          // 500 64-wide quarters
#define NC8 8

typedef __attribute__((ext_vector_type(8))) short short8v;  // 8 bf16 (4 VGPR)
typedef __attribute__((ext_vector_type(4))) float f32x4;    // MFMA acc

#define MFMA16(a,b,c) __builtin_amdgcn_mfma_f32_16x16x32_bf16((a),(b),(c),0,0,0)

#define ASM_VMCNT8() asm volatile("s_waitcnt vmcnt(8)" ::: "memory")
#define ASM_VMCNT4() asm volatile("s_waitcnt vmcnt(4)" ::: "memory")
#define ASM_VMCNT0() asm volatile("s_waitcnt vmcnt(0)" ::: "memory")
#define ASM_LGKM0()  asm volatile("s_waitcnt lgkmcnt(0)" ::: "memory")
#define SCHED_BAR()  __builtin_amdgcn_sched_barrier(0)

__device__ __forceinline__ unsigned short f2bf(float f) {
    return __builtin_bit_cast(unsigned short, __float2bfloat16(f));  // RNE
}
__device__ __forceinline__ float bf2f(unsigned short u) {
    unsigned int v = ((unsigned int)u) << 16;
    return __builtin_bit_cast(float, v);
}
__device__ __forceinline__ void glds16(const unsigned short* g, unsigned short* l) {
    __builtin_amdgcn_global_load_lds(
        (const __attribute__((address_space(1))) unsigned int*)g,
        (__attribute__((address_space(3))) unsigned int*)l, 16, 0, 0);
}
__device__ __forceinline__ void cvt8(const float4& x, const float4& y,
                                     short8v& h, short8v& l) {
    float xs[8] = {x.x, x.y, x.z, x.w, y.x, y.y, y.z, y.w};
    #pragma unroll
    for (int e = 0; e < 8; ++e) {
        unsigned short hb = f2bf(xs[e]);
        h[e] = (short)hb;
        l[e] = (short)f2bf(xs[e] - bf2f(hb));
    }
}
// bijective XCD swizzle (m204 form)
__device__ __forceinline__ int xcd_swz(int wg, int nwg) {
    int q = nwg >> 3, r = nwg & 7;
    int x = wg & 7, o = wg >> 3;
    return (x < r ? x * (q + 1) : r * (q + 1) + (x - r) * q) + o;
}
__device__ __forceinline__ void top2_ins(float& v1, int& i1, float& v2, int& i2,
                                         float nv, int ni) {
    if (nv > v1 || (nv == v1 && ni < i1)) { v2 = v1; i2 = i1; v1 = nv; i1 = ni; }
    else if (nv > v2 || (nv == v2 && ni < i2)) { v2 = nv; i2 = ni; }
}

// ---------------------------------------------------------------------------
// f32 -> hi/lo bf16 planes (Ootomo split, RNE both)
// ---------------------------------------------------------------------------
__global__ __launch_bounds__(256) void vq_cvt(const float* __restrict__ x,
                                              unsigned short* __restrict__ hi,
                                              unsigned short* __restrict__ lo,
                                              size_t n4) {
    size_t stride = (size_t)gridDim.x * 256;
    for (size_t i = (size_t)blockIdx.x * 256 + threadIdx.x; i < n4; i += stride) {
        float4 v = *(const float4*)(x + 4 * i);
        float xs[4] = {v.x, v.y, v.z, v.w};
        ushort4 h, l;
        unsigned short* hp = (unsigned short*)&h;
        unsigned short* lp = (unsigned short*)&l;
        #pragma unroll
        for (int e = 0; e < 4; ++e) {
            hp[e] = f2bf(xs[e]);
            lp[e] = f2bf(xs[e] - bf2f(hp[e]));
        }
        *(ushort4*)(hi + 4 * i) = h;
        *(ushort4*)(lo + 4 * i) = l;
    }
}

// ===========================================================================
// GEMM1 (R7-proven ~900us): 8-phase 3-pass split-bf16, 256x256, BK=32.
// ===========================================================================
#define T8_PHASE(pp, EXTRA)                                                   \
    {                                                                         \
        short8v aAh = *(const short8v*)&smem[cur][0][(wr8 + 2*(pp)) * 512 + lane8];     \
        short8v aAl = *(const short8v*)&smem[cur][1][(wr8 + 2*(pp)) * 512 + lane8];     \
        short8v aBh = *(const short8v*)&smem[cur][0][(wr8 + 2*(pp) + 1) * 512 + lane8]; \
        short8v aBl = *(const short8v*)&smem[cur][1][(wr8 + 2*(pp) + 1) * 512 + lane8]; \
        EXTRA;                                                                \
        SCHED_BAR();                                                          \
        __builtin_amdgcn_s_barrier();                                         \
        ASM_LGKM0();                                                          \
        SCHED_BAR();                                                          \
        __builtin_amdgcn_s_setprio(1);                                        \
        _Pragma("unroll")                                                     \
        for (int nf = 0; nf < 4; ++nf) {                                      \
            acc[2*(pp)][nf]   = MFMA16(aAh, bh[nf], acc[2*(pp)][nf]);         \
            acc[2*(pp)][nf]   = MFMA16(aAh, bl[nf], acc[2*(pp)][nf]);         \
            acc[2*(pp)][nf]   = MFMA16(aAl, bh[nf], acc[2*(pp)][nf]);         \
            acc[2*(pp)+1][nf] = MFMA16(aBh, bh[nf], acc[2*(pp)+1][nf]);       \
            acc[2*(pp)+1][nf] = MFMA16(aBh, bl[nf], acc[2*(pp)+1][nf]);       \
            acc[2*(pp)+1][nf] = MFMA16(aBl, bh[nf], acc[2*(pp)+1][nf]);       \
        }                                                                     \
        __builtin_amdgcn_s_setprio(0);                                        \
        __builtin_amdgcn_s_barrier();                                         \
        SCHED_BAR();                                                          \
    }

__global__ __launch_bounds__(512, 2) void vq_gemm1_t8(
    const unsigned short* __restrict__ Ahp, const unsigned short* __restrict__ Alp,
    const unsigned short* __restrict__ Bhp, const unsigned short* __restrict__ Blp,
    const float* __restrict__ bias,
    unsigned short* __restrict__ Phi, unsigned short* __restrict__ Plo)
{
    __shared__ unsigned short smem[2][4][8192];   // 128 KiB
    const int wg = xcd_swz(blockIdx.x, NTILE1);
    const int mt = (wg >> 2) * 256;   // V
    const int nt = (wg & 3) * 256;    // D
    const int lane = threadIdx.x & 63, w = threadIdx.x >> 6;
    const int wr = w >> 2, wc = w & 3;
    const int r16 = lane & 15, kg = lane >> 4;
    const int lane8 = lane * 8, wr8 = wr * 8, wc4 = wc * 4;
    const int pw = w >> 1;
    const unsigned short* gplane = (pw == 0) ? Ahp : (pw == 1) ? Alp
                                   : (pw == 2) ? Bhp : Blp;
    const int baseRow = (pw < 2 ? mt : nt) + (w & 1) * 128 + r16;
    const unsigned short* gsrc = gplane + (size_t)baseRow * CD_ + kg * 8;
    unsigned short* lb0 = &smem[0][pw][(w & 1) * 4096 + lane8];
    unsigned short* lb1 = &smem[1][pw][(w & 1) * 4096 + lane8];

    f32x4 acc[8][4];
    #pragma unroll
    for (int i = 0; i < 8; ++i)
        #pragma unroll
        for (int j = 0; j < 4; ++j) acc[i][j] = (f32x4){0.f, 0.f, 0.f, 0.f};

    #pragma unroll
    for (int q = 0; q < 8; ++q)
        glds16(gsrc + (size_t)q * 16 * CD_, lb0 + q * 512);
    ASM_VMCNT0();
    __builtin_amdgcn_s_barrier();
    SCHED_BAR();
    const int NT = CD_ / 32;
    for (int t = 0; t < NT; ++t) {
        const int cur = t & 1;
        unsigned short* lbN = cur ? lb0 : lb1;
        short8v bh[4], bl[4];
        #pragma unroll
        for (int nf = 0; nf < 4; ++nf) {
            bh[nf] = *(const short8v*)&smem[cur][2][(wc4 + nf) * 512 + lane8];
            bl[nf] = *(const short8v*)&smem[cur][3][(wc4 + nf) * 512 + lane8];
        }
        T8_PHASE(0,
            if (t + 1 < NT) {
                const size_t kof = (size_t)(t + 1) * 32;
                _Pragma("unroll")
                for (int q = 0; q < 8; ++q)
                    glds16(gsrc + kof + (size_t)q * 16 * CD_, lbN + q * 512);
            })
        T8_PHASE(1, (void)0)
        T8_PHASE(2, (void)0)
        T8_PHASE(3, if (t + 1 < NT) { ASM_VMCNT0(); })
    }

    // epilogue: +bias, split to hi/lo planes.  C/D: col=lane&15, row=kg*4+r
    #pragma unroll
    for (int nf = 0; nf < 4; ++nf) {
        const int col = nt + wc * 64 + nf * 16 + r16;
        const float bv = bias[col];
        #pragma unroll
        for (int mf = 0; mf < 8; ++mf) {
            const int rbase = mt + wr * 128 + mf * 16 + kg * 4;
            #pragma unroll
            for (int r = 0; r < 4; ++r) {
                float vv = acc[mf][nf][r] + bv;
                unsigned short h = f2bf(vv);
                unsigned short l = f2bf(vv - bf2f(h));
                size_t o = (size_t)(rbase + r) * D_ + col;
                Phi[o] = h; Plo[o] = l;
            }
        }
    }
}

// ===========================================================================
// GEMM2 coarse 1-pass (R11-passed): hi planes only, 256x256, BK=32, 64 KiB
// LDS -> 2 blocks/CU, counted vmcnt(4), per-(row, 64-quarter) top-2 partials.
// ===========================================================================
__global__ __launch_bounds__(512, 2) void vq_gemm2_c1(
    const unsigned short* __restrict__ Eh, const unsigned short* __restrict__ Ph,
    const float* __restrict__ ninv,
    float* __restrict__ parrv, int* __restrict__ parri)
{
    __shared__ unsigned short smem[2][2][8192];   // 64 KiB
    const int wg = xcd_swz(blockIdx.x, (NR/256) * VT2);
    const int nid = wg >> 3;          // 0..124 V-tile
    const int mt = (wg & 7) * 256;    // rows
    const int nt = nid * 256;         // V
    const int lane = threadIdx.x & 63, w = threadIdx.x >> 6;
    const int wr = w >> 2, wc = w & 3;
    const int r16 = lane & 15, kg = lane >> 4;
    const int lane8 = lane * 8, wr8 = wr * 8, wc4 = wc * 4;
    const int pw = w >> 2;
    const int sq = (w & 3) * 4;
    const unsigned short* gp = pw ? Ph : Eh;
    const int baseRow = (pw ? nt : mt) + sq * 16 + r16;
    const unsigned short* gsrc = gp + (size_t)baseRow * D_ + kg * 8;
    unsigned short* lb0 = &smem[0][pw][sq * 512 + lane8];
    unsigned short* lb1 = &smem[1][pw][sq * 512 + lane8];

    f32x4 acc[8][4];
    #pragma unroll
    for (int i = 0; i < 8; ++i)
        #pragma unroll
        for (int j = 0; j < 4; ++j) acc[i][j] = (f32x4){0.f, 0.f, 0.f, 0.f};

    #pragma unroll
    for (int q = 0; q < 4; ++q)
        glds16(gsrc + (size_t)q * 16 * D_, lb0 + q * 512);
    ASM_VMCNT0();
    __builtin_amdgcn_s_barrier();
    SCHED_BAR();

    const int NT = D_ / 32;   // 32
    for (int t = 0; t < NT; ++t) {
        const int cur = t & 1;
        if (t + 1 < NT) {
            unsigned short* lb = cur ? lb0 : lb1;
            const size_t kof = (size_t)(t + 1) * 32;
            #pragma unroll
            for (int q = 0; q < 4; ++q)
                glds16(gsrc + kof + (size_t)q * 16 * D_, lb + q * 512);
            ASM_VMCNT4();
        } else {
            ASM_VMCNT0();
        }
        __builtin_amdgcn_s_barrier();
        SCHED_BAR();
        short8v bfr[4];
        #pragma unroll
        for (int nf = 0; nf < 4; ++nf)
            bfr[nf] = *(const short8v*)&smem[cur][1][(wc4 + nf) * 512 + lane8];
        #pragma unroll
        for (int g = 0; g < 4; ++g) {
            short8v a0 = *(const short8v*)&smem[cur][0][(wr8 + 2*g) * 512 + lane8];
            short8v a1 = *(const short8v*)&smem[cur][0][(wr8 + 2*g + 1) * 512 + lane8];
            __builtin_amdgcn_s_setprio(1);
            #pragma unroll
            for (int nf = 0; nf < 4; ++nf) {
                acc[2*g][nf]   = MFMA16(a0, bfr[nf], acc[2*g][nf]);
                acc[2*g+1][nf] = MFMA16(a1, bfr[nf], acc[2*g+1][nf]);
            }
            __builtin_amdgcn_s_setprio(0);
        }
        ASM_LGKM0();
        __builtin_amdgcn_s_barrier();
        SCHED_BAR();
    }

    // per-(row, quarter) top-2; ties -> smallest v
    const int qid = nid * 4 + wc;     // 0..499
    float nv[4];
    #pragma unroll
    for (int nf = 0; nf < 4; ++nf) nv[nf] = ninv[nt + wc * 64 + nf * 16 + r16];
    #pragma unroll
    for (int mf = 0; mf < 8; ++mf) {
        #pragma unroll
        for (int r = 0; r < 4; ++r) {
            float v1 = -INFINITY, v2 = -INFINITY;
            int i1 = 0x7fffffff, i2 = 0x7fffffff;
            #pragma unroll
            for (int nf = 0; nf < 4; ++nf) {
                float s = acc[mf][nf][r] * nv[nf];
                int ci = nt + wc * 64 + nf * 16 + r16;
                top2_ins(v1, i1, v2, i2, s, ci);
            }
            #pragma unroll
            for (int m = 8; m >= 1; m >>= 1) {
                float ov1 = __shfl_xor(v1, m, 16); int oi1 = __shfl_xor(i1, m, 16);
                float ov2 = __shfl_xor(v2, m, 16); int oi2 = __shfl_xor(i2, m, 16);
                top2_ins(v1, i1, v2, i2, ov1, oi1);
                top2_ins(v1, i1, v2, i2, ov2, oi2);
            }
            if (r16 == 0) {
                const int row = mt + wr * 128 + mf * 16 + kg * 4 + r;
                size_t off = (size_t)row * (NQ4 * 2) + qid * 2;
                parrv[off] = v1;     parri[off] = i1;
                parrv[off + 1] = v2; parri[off + 1] = i2;
            }
        }
    }
}

// ---------------------------------------------------------------------------
// per-row global top-8: ONE WAVE PER ROW (R5-validated structure).
// lane l holds slots l, l+64, ..., coalesced loads; 8 rounds of 64-wide
// shuffle-argmax + invalidate-by-index (indices unique per row).
// ---------------------------------------------------------------------------
__global__ __launch_bounds__(256) void vq_top8w(const float* __restrict__ parrv,
                                                const int* __restrict__ parri,
                                                int* __restrict__ cand) {
    const int row = blockIdx.x * 4 + (threadIdx.x >> 6);
    const int lane = threadIdx.x & 63;
    float v[16]; int id[16];
    #pragma unroll
    for (int q = 0; q < 16; ++q) {
        int s = lane + q * 64;
        if (s < NQ4 * 2) {
            v[q] = parrv[(size_t)row * (NQ4 * 2) + s];
            id[q] = parri[(size_t)row * (NQ4 * 2) + s];
        } else { v[q] = -INFINITY; id[q] = 0x7fffffff; }
    }
    for (int k = 0; k < NC8; ++k) {
        float bv = -INFINITY; int bi = 0x7fffffff;
        #pragma unroll
        for (int q = 0; q < 16; ++q)
            if (v[q] > bv || (v[q] == bv && id[q] < bi)) { bv = v[q]; bi = id[q]; }
        #pragma unroll
        for (int m = 32; m >= 1; m >>= 1) {
            float ov = __shfl_xor(bv, m, 64); int oi = __shfl_xor(bi, m, 64);
            if (ov > bv || (ov == bv && oi < bi)) { bv = ov; bi = oi; }
        }
        if (lane == 0) cand[row * NC8 + k] = bi;
        #pragma unroll
        for (int q = 0; q < 16; ++q)
            if (id[q] == bi) v[q] = -INFINITY;   // idx unique per row
    }
}

// ---------------------------------------------------------------------------
// exact f64 rescore of the 8 candidates -> final index (deterministic)
// ---------------------------------------------------------------------------
__global__ __launch_bounds__(256) void vq_rescore8(
    const unsigned short* __restrict__ eh, const unsigned short* __restrict__ el,
    const unsigned short* __restrict__ ph, const unsigned short* __restrict__ pl,
    const float* __restrict__ ninv, const int* __restrict__ cand,
    int* __restrict__ idxw, float* __restrict__ outI) {
    __shared__ float e[D_];
    __shared__ double wsum[NC8][4];
    const int row = blockIdx.x;
    const int tid = threadIdx.x, lane = tid & 63, wv = tid >> 6;
    {
        ushort4 h = *(const ushort4*)(eh + (size_t)row * D_ + tid * 4);
        ushort4 l = *(const ushort4*)(el + (size_t)row * D_ + tid * 4);
        const unsigned short* hp = (const unsigned short*)&h;
        const unsigned short* lp = (const unsigned short*)&l;
        #pragma unroll
        for (int j = 0; j < 4; ++j)
            e[tid * 4 + j] = bf2f(hp[j]) + bf2f(lp[j]);
    }
    __syncthreads();
    for (int c = 0; c < NC8; ++c) {
        int cv = cand[row * NC8 + c];
        ushort4 h = *(const ushort4*)(ph + (size_t)cv * D_ + tid * 4);
        ushort4 l = *(const ushort4*)(pl + (size_t)cv * D_ + tid * 4);
        const unsigned short* hp = (const unsigned short*)&h;
        const unsigned short* lp = (const unsigned short*)&l;
        double s = 0.0;
        #pragma unroll
        for (int j = 0; j < 4; ++j)
            s += (double)e[tid * 4 + j] * (double)(bf2f(hp[j]) + bf2f(lp[j]));
        #pragma unroll
        for (int off = 32; off >= 1; off >>= 1) s += __shfl_down(s, off);
        if (lane == 0) wsum[c][wv] = s;
    }
    __syncthreads();
    if (tid == 0) {
        double best = -1.0e300; int bi = 0x7fffffff;
        for (int c = 0; c < NC8; ++c) {
            int cv = cand[row * NC8 + c];
            double s = (wsum[c][0] + wsum[c][1] + wsum[c][2] + wsum[c][3])
                       * (double)ninv[cv];
            if (s > best || (s == best && cv < bi)) { best = s; bi = cv; }
        }
        idxw[row] = bi;
        outI[row] = (float)bi;
    }
}

// ---------------------------------------------------------------------------
__global__ __launch_bounds__(256) void vq_norms_pl(const unsigned short* __restrict__ ph,
                                                   const unsigned short* __restrict__ pl,
                                                   float* __restrict__ ninv) {
    const int row  = blockIdx.x * 4 + (threadIdx.x >> 6);
    const int lane = threadIdx.x & 63;
    float s = 0.f;
    #pragma unroll
    for (int q = 0; q < 2; ++q) {
        size_t o = (size_t)row * D_ + q * 512 + lane * 8;
        short8v h = *(const short8v*)(ph + o);
        short8v l = *(const short8v*)(pl + o);
        #pragma unroll
        for (int e = 0; e < 8; ++e) {
            float x = bf2f((unsigned short)h[e]) + bf2f((unsigned short)l[e]);
            s += x * x;
        }
    }
    #pragma unroll
    for (int off = 32; off >= 1; off >>= 1) s += __shfl_down(s, off);
    if (lane == 0) ninv[row] = 1.0f / fmaxf(sqrtf(s), 1e-12f);
}

__global__ __launch_bounds__(256) void vq_transpose_cvt(const float* __restrict__ z,
                                                        unsigned short* __restrict__ ehi,
                                                        unsigned short* __restrict__ elo) {
    __shared__ float tile[64][65];
    const int b = blockIdx.z, t0 = blockIdx.x * 64, d0 = blockIdx.y * 64;
    const int lane = threadIdx.x & 63, sub = threadIdx.x >> 6;
    for (int dd = sub; dd < 64; dd += 4)
        tile[dd][lane] = z[((size_t)b * D_ + d0 + dd) * T_ + t0 + lane];
    __syncthreads();
    for (int tt = sub; tt < 64; tt += 4) {
        float v = tile[lane][tt];
        unsigned short h = f2bf(v);
        unsigned short l = f2bf(v - bf2f(h));
        size_t o = (size_t)(b * T_ + t0 + tt) * D_ + d0 + lane;
        ehi[o] = h; elo[o] = l;
    }
}

__global__ __launch_bounds__(256) void vq_gather_pl(const unsigned short* __restrict__ ph,
                                                    const unsigned short* __restrict__ pl,
                                                    const int* __restrict__ idxw,
                                                    const float* __restrict__ z,
                                                    float* __restrict__ out0,
                                                    float* __restrict__ lpart) {
    __shared__ float zq[64][65];
    __shared__ int idx_s[64];
    __shared__ float wsum[4];
    const int b = blockIdx.z, t0 = blockIdx.x * 64, d0 = blockIdx.y * 64;
    const int tid = threadIdx.x;
    const int lane = tid & 63, sub = tid >> 6;
    if (tid < 64) idx_s[tid] = idxw[b * T_ + t0 + tid];
    __syncthreads();
    for (int tt = sub; tt < 64; tt += 4) {
        size_t o = (size_t)idx_s[tt] * D_ + d0 + lane;
        zq[tt][lane] = bf2f(ph[o]) + bf2f(pl[o]);
    }
    __syncthreads();
    float lacc = 0.f;
    for (int dd = sub; dd < 64; dd += 4) {
        const size_t base = ((size_t)b * D_ + d0 + dd) * T_ + t0 + lane;
        float q = zq[lane][dd];
        float zv = z[base];
        out0[base] = q;
        float dv = zv - q;
        lacc += dv * dv;
    }
    #pragma unroll
    for (int off = 32; off >= 1; off >>= 1) lacc += __shfl_down(lacc, off);
    if (lane == 0) wsum[sub] = lacc;
    __syncthreads();
    if (tid == 0)
        lpart[(blockIdx.z * 16 + blockIdx.y) * 8 + blockIdx.x] =
            wsum[0] + wsum[1] + wsum[2] + wsum[3];
}

__global__ void vq_loss(const float* __restrict__ lpart, float* __restrict__ outL) {
    const int b = threadIdx.x;
    if (b >= B_) return;
    float s = 0.f;
    for (int q = 0; q < 128; q++) s += lpart[b * 128 + q];
    s /= (float)(D_ * T_);
    outL[b]      = s;
    outL[B_ + b] = s;
}

// ===========================================================================
extern "C" void kernel_launch(void* const* d_in, const int* in_sizes, int n_in,
                              void* d_out, int out_size, void* d_ws, size_t ws_size,
                              hipStream_t stream) {
    const float* z        = (const float*)d_in[0];   // [B, D, T]
    const float* codebook = (const float*)d_in[1];   // [V, CD]
    const float* cb_w     = (const float*)d_in[2];   // [D, CD]
    const float* cb_b     = (const float*)d_in[3];   // [D]

    float* out0 = (float*)d_out;
    float* outI = out0 + (size_t)B_*D_*T_;
    float* outL = outI + NR;

    char* p = (char*)d_ws;
    auto alloc = [&](size_t bytes) { char* r = p; p += (bytes + 255) & ~(size_t)255; return r; };
    unsigned short* w_hi = (unsigned short*)alloc((size_t)D_ * CD_ * 2);
    unsigned short* w_lo = (unsigned short*)alloc((size_t)D_ * CD_ * 2);
    unsigned short* p_hi = (unsigned short*)alloc((size_t)V_ * D_ * 2);
    unsigned short* p_lo = (unsigned short*)alloc((size_t)V_ * D_ * 2);
    unsigned short* e_hi = (unsigned short*)alloc((size_t)NR * D_ * 2);
    unsigned short* e_lo = (unsigned short*)alloc((size_t)NR * D_ * 2);
    float* ninv  = (float*)alloc((size_t)V_ * 4);
    float* parrv = (float*)alloc((size_t)NR * NQ4 * 2 * 4);   // 16 MB
    int*   parri = (int*)  alloc((size_t)NR * NQ4 * 2 * 4);   // 16 MB
    int*   cand  = (int*)  alloc((size_t)NR * NC8 * 4);
    int*   idxw  = (int*)  alloc((size_t)NR * 4);
    float* lpart = (float*)alloc((size_t)2048 * 4);
    unsigned short* c_hi = (unsigned short*)alloc((size_t)V_ * CD_ * 2);
    unsigned short* c_lo = (unsigned short*)alloc((size_t)V_ * CD_ * 2);
    // ~720 MB total; R10 proved >= 1.21 GB available

    vq_cvt<<<512, 256, 0, stream>>>(cb_w, w_hi, w_lo, (size_t)D_ * CD_ / 4);
    vq_transpose_cvt<<<dim3(T_/64, D_/64, B_), 256, 0, stream>>>(z, e_hi, e_lo);
    vq_cvt<<<4096, 256, 0, stream>>>(codebook, c_hi, c_lo, (size_t)V_ * CD_ / 4);

    vq_gemm1_t8<<<NTILE1, 512, 0, stream>>>(c_hi, c_lo, w_hi, w_lo,
                                            cb_b, p_hi, p_lo);
    vq_norms_pl<<<V_/4, 256, 0, stream>>>(p_hi, p_lo, ninv);
    vq_gemm2_c1<<<(NR/256) * VT2, 512, 0, stream>>>(e_hi, p_hi, ninv, parrv, parri);
    vq_top8w<<<NR/4, 256, 0, stream>>>(parrv, parri, cand);
    vq_rescore8<<<NR, 256, 0, stream>>>(e_hi, e_lo, p_hi, p_lo, ninv, cand,
                                        idxw, outI);
    vq_gather_pl<<<dim3(T_/64, D_/64, B_), 256, 0, stream>>>(p_hi, p_lo, idxw, z,
                                                             out0, lpart);
    vq_loss<<<1, 64, 0, stream>>>(lpart, outL);
}

// Round 13
// 1538.640 us; speedup vs baseline: 1.6548x; 1.2124x over previous
//
#include <hip/hip_runtime.h>
#include <hip/hip_bf16.h>
#include <math.h>

#define B_  4
#define D_  1024
#define T_  512
#define V_  32000
#define CD_ 4096
#define NR  (B_*T_)          // 2048 rows
#define VT2 (V_/256)         // 125 v-tiles (256-wide)
#define NTILE1 ((V_/256)*(D_/256))   // 500 gemm1 tiles

typedef __attribute__((ext_vector_type(8))) short short8v;  // 8 bf16 (4 VGPR)
typedef __attribute__((ext_vector_type(4))) float f32x4;    // MFMA acc

#define MFMA16(a,b,c) __builtin_amdgcn_mfma_f32_16x16x32_bf16((a),(b),(c),0,0,0)

#define ASM_VMCNT8() asm volatile("s_waitcnt vmcnt(8)" ::: "memory")
#define ASM_VMCNT0() asm volatile("s_waitcnt vmcnt(0)" ::: "memory")
#define ASM_LGKM0()  asm volatile("s_waitcnt lgkmcnt(0)" ::: "memory")
#define SCHED_BAR()  __builtin_amdgcn_sched_barrier(0)

__device__ __forceinline__ unsigned short f2bf(float f) {
    return __builtin_bit_cast(unsigned short, __float2bfloat16(f));  // RNE
}
__device__ __forceinline__ float bf2f(unsigned short u) {
    unsigned int v = ((unsigned int)u) << 16;
    return __builtin_bit_cast(float, v);
}
__device__ __forceinline__ void glds16(const unsigned short* g, unsigned short* l) {
    __builtin_amdgcn_global_load_lds(
        (const __attribute__((address_space(1))) unsigned int*)g,
        (__attribute__((address_space(3))) unsigned int*)l, 16, 0, 0);
}
__device__ __forceinline__ void cvt8(const float4& x, const float4& y,
                                     short8v& h, short8v& l) {
    float xs[8] = {x.x, x.y, x.z, x.w, y.x, y.y, y.z, y.w};
    #pragma unroll
    for (int e = 0; e < 8; ++e) {
        unsigned short hb = f2bf(xs[e]);
        h[e] = (short)hb;
        l[e] = (short)f2bf(xs[e] - bf2f(hb));
    }
}
// bijective XCD swizzle (m204 form)
__device__ __forceinline__ int xcd_swz(int wg, int nwg) {
    int q = nwg >> 3, r = nwg & 7;
    int x = wg & 7, o = wg >> 3;
    return (x < r ? x * (q + 1) : r * (q + 1) + (x - r) * q) + o;
}

// ---------------------------------------------------------------------------
// f32 -> hi/lo bf16 planes (Ootomo split, RNE both), 8 elems/thread,
// 16-B loads x2 and 16-B stores x2 (write-combine friendly)
// ---------------------------------------------------------------------------
__global__ __launch_bounds__(256) void vq_cvt8(const float* __restrict__ x,
                                               unsigned short* __restrict__ hi,
                                               unsigned short* __restrict__ lo,
                                               size_t n8) {
    size_t stride = (size_t)gridDim.x * 256;
    for (size_t i = (size_t)blockIdx.x * 256 + threadIdx.x; i < n8; i += stride) {
        float4 a = *(const float4*)(x + 8 * i);
        float4 b = *(const float4*)(x + 8 * i + 4);
        short8v h, l;
        cvt8(a, b, h, l);
        *(short8v*)(hi + 8 * i) = h;
        *(short8v*)(lo + 8 * i) = l;
    }
}

// ===========================================================================
// GEMM1 (R7-proven ~897us): 8-phase 3-pass split-bf16, 256x256, BK=32.
// LDS chunk-linear subtiles (0 bank conflicts, measured).
// ===========================================================================
#define T8_PHASE(pp, EXTRA)                                                   \
    {                                                                         \
        short8v aAh = *(const short8v*)&smem[cur][0][(wr8 + 2*(pp)) * 512 + lane8];     \
        short8v aAl = *(const short8v*)&smem[cur][1][(wr8 + 2*(pp)) * 512 + lane8];     \
        short8v aBh = *(const short8v*)&smem[cur][0][(wr8 + 2*(pp) + 1) * 512 + lane8]; \
        short8v aBl = *(const short8v*)&smem[cur][1][(wr8 + 2*(pp) + 1) * 512 + lane8]; \
        EXTRA;                                                                \
        SCHED_BAR();                                                          \
        __builtin_amdgcn_s_barrier();                                         \
        ASM_LGKM0();                                                          \
        SCHED_BAR();                                                          \
        __builtin_amdgcn_s_setprio(1);                                        \
        _Pragma("unroll")                                                     \
        for (int nf = 0; nf < 4; ++nf) {                                      \
            acc[2*(pp)][nf]   = MFMA16(aAh, bh[nf], acc[2*(pp)][nf]);         \
            acc[2*(pp)][nf]   = MFMA16(aAh, bl[nf], acc[2*(pp)][nf]);         \
            acc[2*(pp)][nf]   = MFMA16(aAl, bh[nf], acc[2*(pp)][nf]);         \
            acc[2*(pp)+1][nf] = MFMA16(aBh, bh[nf], acc[2*(pp)+1][nf]);       \
            acc[2*(pp)+1][nf] = MFMA16(aBh, bl[nf], acc[2*(pp)+1][nf]);       \
            acc[2*(pp)+1][nf] = MFMA16(aBl, bh[nf], acc[2*(pp)+1][nf]);       \
        }                                                                     \
        __builtin_amdgcn_s_setprio(0);                                        \
        __builtin_amdgcn_s_barrier();                                         \
        SCHED_BAR();                                                          \
    }

__global__ __launch_bounds__(512, 2) void vq_gemm1_t8(
    const unsigned short* __restrict__ Ahp, const unsigned short* __restrict__ Alp,
    const unsigned short* __restrict__ Bhp, const unsigned short* __restrict__ Blp,
    const float* __restrict__ bias,
    unsigned short* __restrict__ Phi, unsigned short* __restrict__ Plo)
{
    __shared__ unsigned short smem[2][4][8192];   // 128 KiB
    const int wg = xcd_swz(blockIdx.x, NTILE1);
    const int mt = (wg >> 2) * 256;   // V
    const int nt = (wg & 3) * 256;    // D
    const int lane = threadIdx.x & 63, w = threadIdx.x >> 6;
    const int wr = w >> 2, wc = w & 3;
    const int r16 = lane & 15, kg = lane >> 4;
    const int lane8 = lane * 8, wr8 = wr * 8, wc4 = wc * 4;
    const int pw = w >> 1;
    const unsigned short* gplane = (pw == 0) ? Ahp : (pw == 1) ? Alp
                                   : (pw == 2) ? Bhp : Blp;
    const int baseRow = (pw < 2 ? mt : nt) + (w & 1) * 128 + r16;
    const unsigned short* gsrc = gplane + (size_t)baseRow * CD_ + kg * 8;
    unsigned short* lb0 = &smem[0][pw][(w & 1) * 4096 + lane8];
    unsigned short* lb1 = &smem[1][pw][(w & 1) * 4096 + lane8];

    f32x4 acc[8][4];
    #pragma unroll
    for (int i = 0; i < 8; ++i)
        #pragma unroll
        for (int j = 0; j < 4; ++j) acc[i][j] = (f32x4){0.f, 0.f, 0.f, 0.f};

    #pragma unroll
    for (int q = 0; q < 8; ++q)
        glds16(gsrc + (size_t)q * 16 * CD_, lb0 + q * 512);
    ASM_VMCNT0();
    __builtin_amdgcn_s_barrier();
    SCHED_BAR();
    const int NT = CD_ / 32;
    for (int t = 0; t < NT; ++t) {
        const int cur = t & 1;
        unsigned short* lbN = cur ? lb0 : lb1;
        short8v bh[4], bl[4];
        #pragma unroll
        for (int nf = 0; nf < 4; ++nf) {
            bh[nf] = *(const short8v*)&smem[cur][2][(wc4 + nf) * 512 + lane8];
            bl[nf] = *(const short8v*)&smem[cur][3][(wc4 + nf) * 512 + lane8];
        }
        T8_PHASE(0,
            if (t + 1 < NT) {
                const size_t kof = (size_t)(t + 1) * 32;
                _Pragma("unroll")
                for (int q = 0; q < 8; ++q)
                    glds16(gsrc + kof + (size_t)q * 16 * CD_, lbN + q * 512);
            })
        T8_PHASE(1, (void)0)
        T8_PHASE(2, (void)0)
        T8_PHASE(3, if (t + 1 < NT) { ASM_VMCNT0(); })
    }

    // epilogue: +bias, split to hi/lo planes.  C/D: col=lane&15, row=kg*4+r
    #pragma unroll
    for (int nf = 0; nf < 4; ++nf) {
        const int col = nt + wc * 64 + nf * 16 + r16;
        const float bv = bias[col];
        #pragma unroll
        for (int mf = 0; mf < 8; ++mf) {
            const int rbase = mt + wr * 128 + mf * 16 + kg * 4;
            #pragma unroll
            for (int r = 0; r < 4; ++r) {
                float vv = acc[mf][nf][r] + bv;
                unsigned short h = f2bf(vv);
                unsigned short l = f2bf(vv - bf2f(h));
                size_t o = (size_t)(rbase + r) * D_ + col;
                Phi[o] = h; Plo[o] = l;
            }
        }
    }
}

// ===========================================================================
// GEMM2 (R7/R10-proven ~330us): 8-phase 3-pass split-bf16, 256x256,
// fused scaled argmax per 256-v tile
// ===========================================================================
__global__ __launch_bounds__(512, 2) void vq_gemm2_t8(
    const unsigned short* __restrict__ Ahp, const unsigned short* __restrict__ Alp,
    const unsigned short* __restrict__ Bhp, const unsigned short* __restrict__ Blp,
    const float* __restrict__ ninv,
    float* __restrict__ pmax, int* __restrict__ pidx)
{
    __shared__ unsigned short smem[2][4][8192];   // 128 KiB
    const int wg = xcd_swz(blockIdx.x, (NR/256) * VT2);
    const int nid = wg >> 3;          // 0..124 V-tile
    const int mt = (wg & 7) * 256;    // rows
    const int nt = nid * 256;         // V

    f32x4 acc[8][4];
    #pragma unroll
    for (int i = 0; i < 8; ++i)
        #pragma unroll
        for (int j = 0; j < 4; ++j) acc[i][j] = (f32x4){0.f, 0.f, 0.f, 0.f};
    const int lane = threadIdx.x & 63, w = threadIdx.x >> 6;
    const int wr = w >> 2, wc = w & 3;
    const int r16 = lane & 15, kg = lane >> 4;
    const int lane8 = lane * 8, wr8 = wr * 8, wc4 = wc * 4;
    const int pw = w >> 1;
    const unsigned short* gplane = (pw == 0) ? Ahp : (pw == 1) ? Alp
                                   : (pw == 2) ? Bhp : Blp;
    const int baseRow = (pw < 2 ? mt : nt) + (w & 1) * 128 + r16;
    const unsigned short* gsrc = gplane + (size_t)baseRow * D_ + kg * 8;
    unsigned short* lb0 = &smem[0][pw][(w & 1) * 4096 + lane8];
    unsigned short* lb1 = &smem[1][pw][(w & 1) * 4096 + lane8];
    #pragma unroll
    for (int q = 0; q < 8; ++q)
        glds16(gsrc + (size_t)q * 16 * D_, lb0 + q * 512);
    ASM_VMCNT0();
    __builtin_amdgcn_s_barrier();
    SCHED_BAR();
    const int NT = D_ / 32;
    for (int t = 0; t < NT; ++t) {
        const int cur = t & 1;
        unsigned short* lbN = cur ? lb0 : lb1;
        short8v bh[4], bl[4];
        #pragma unroll
        for (int nf = 0; nf < 4; ++nf) {
            bh[nf] = *(const short8v*)&smem[cur][2][(wc4 + nf) * 512 + lane8];
            bl[nf] = *(const short8v*)&smem[cur][3][(wc4 + nf) * 512 + lane8];
        }
        T8_PHASE(0,
            if (t + 1 < NT) {
                const size_t kof = (size_t)(t + 1) * 32;
                _Pragma("unroll")
                for (int q = 0; q < 8; ++q)
                    glds16(gsrc + kof + (size_t)q * 16 * D_, lbN + q * 512);
            })
        T8_PHASE(1, (void)0)
        T8_PHASE(2, (void)0)
        T8_PHASE(3, if (t + 1 < NT) { ASM_VMCNT0(); })
    }

    // scaled argmax; ties -> smallest v (ascending, strict >)
    float* redv = (float*)&smem[0][0][0];      // [256][4] f32
    int*   redi = (int*)&smem[0][0][2048];     // [256][4] i32
    float nv[4];
    #pragma unroll
    for (int nf = 0; nf < 4; ++nf) nv[nf] = ninv[nt + wc * 64 + nf * 16 + r16];
    #pragma unroll
    for (int mf = 0; mf < 8; ++mf) {
        #pragma unroll
        for (int r = 0; r < 4; ++r) {
            float best = -INFINITY; int bi = 0x7fffffff;
            #pragma unroll
            for (int nf = 0; nf < 4; ++nf) {
                float v = acc[mf][nf][r] * nv[nf];
                int ci = nt + wc * 64 + nf * 16 + r16;
                if (v > best || (v == best && ci < bi)) { best = v; bi = ci; }
            }
            #pragma unroll
            for (int m = 8; m >= 1; m >>= 1) {
                float ov = __shfl_xor(best, m, 16);
                int   oi = __shfl_xor(bi,   m, 16);
                if (ov > best || (ov == best && oi < bi)) { best = ov; bi = oi; }
            }
            if (r16 == 0) {
                int rl = wr * 128 + mf * 16 + kg * 4 + r;
                redv[rl * 4 + wc] = best; redi[rl * 4 + wc] = bi;
            }
        }
    }
    __builtin_amdgcn_s_barrier();
    if (threadIdx.x < 256) {
        float best = -INFINITY; int bi = 0x7fffffff;
        #pragma unroll
        for (int c = 0; c < 4; ++c) {
            float v = redv[threadIdx.x * 4 + c];
            int   i = redi[threadIdx.x * 4 + c];
            if (v > best || (v == best && i < bi)) { best = v; bi = i; }
        }
        size_t o = (size_t)(mt + threadIdx.x) * VT2 + nid;
        pmax[o] = best; pidx[o] = bi;
    }
}

// ---------------------------------------------------------------------------
__global__ __launch_bounds__(256) void vq_norms_pl(const unsigned short* __restrict__ ph,
                                                   const unsigned short* __restrict__ pl,
                                                   float* __restrict__ ninv) {
    const int row  = blockIdx.x * 4 + (threadIdx.x >> 6);
    const int lane = threadIdx.x & 63;
    float s = 0.f;
    #pragma unroll
    for (int q = 0; q < 2; ++q) {
        size_t o = (size_t)row * D_ + q * 512 + lane * 8;
        short8v h = *(const short8v*)(ph + o);
        short8v l = *(const short8v*)(pl + o);
        #pragma unroll
        for (int e = 0; e < 8; ++e) {
            float x = bf2f((unsigned short)h[e]) + bf2f((unsigned short)l[e]);
            s += x * x;
        }
    }
    #pragma unroll
    for (int off = 32; off >= 1; off >>= 1) s += __shfl_down(s, off);
    if (lane == 0) ninv[row] = 1.0f / fmaxf(sqrtf(s), 1e-12f);
}

__global__ __launch_bounds__(256) void vq_transpose_cvt(const float* __restrict__ z,
                                                        unsigned short* __restrict__ ehi,
                                                        unsigned short* __restrict__ elo) {
    __shared__ float tile[64][65];
    const int b = blockIdx.z, t0 = blockIdx.x * 64, d0 = blockIdx.y * 64;
    const int lane = threadIdx.x & 63, sub = threadIdx.x >> 6;
    for (int dd = sub; dd < 64; dd += 4)
        tile[dd][lane] = z[((size_t)b * D_ + d0 + dd) * T_ + t0 + lane];
    __syncthreads();
    for (int tt = sub; tt < 64; tt += 4) {
        float v = tile[lane][tt];
        unsigned short h = f2bf(v);
        unsigned short l = f2bf(v - bf2f(h));
        size_t o = (size_t)(b * T_ + t0 + tt) * D_ + d0 + lane;
        ehi[o] = h; elo[o] = l;
    }
}

__global__ __launch_bounds__(256) void vq_argmerge(const float* __restrict__ pmax,
                                                   const int* __restrict__ pidx,
                                                   int* __restrict__ idxw,
                                                   float* __restrict__ outI,
                                                   int vt) {
    const int i = blockIdx.x * 256 + threadIdx.x;
    if (i >= NR) return;
    float best = -INFINITY; int bi = 0;
    for (int c = 0; c < vt; c++) {
        float v = pmax[(size_t)i * vt + c];
        int   ii = pidx[(size_t)i * vt + c];
        if (v > best || (v == best && ii < bi)) { best = v; bi = ii; }
    }
    idxw[i] = bi;
    outI[i] = (float)bi;
}

__global__ __launch_bounds__(256) void vq_gather_pl(const unsigned short* __restrict__ ph,
                                                    const unsigned short* __restrict__ pl,
                                                    const int* __restrict__ idxw,
                                                    const float* __restrict__ z,
                                                    float* __restrict__ out0,
                                                    float* __restrict__ lpart) {
    __shared__ float zq[64][65];
    __shared__ int idx_s[64];
    __shared__ float wsum[4];
    const int b = blockIdx.z, t0 = blockIdx.x * 64, d0 = blockIdx.y * 64;
    const int tid = threadIdx.x;
    const int lane = tid & 63, sub = tid >> 6;
    if (tid < 64) idx_s[tid] = idxw[b * T_ + t0 + tid];
    __syncthreads();
    for (int tt = sub; tt < 64; tt += 4) {
        size_t o = (size_t)idx_s[tt] * D_ + d0 + lane;
        zq[tt][lane] = bf2f(ph[o]) + bf2f(pl[o]);
    }
    __syncthreads();
    float lacc = 0.f;
    for (int dd = sub; dd < 64; dd += 4) {
        const size_t base = ((size_t)b * D_ + d0 + dd) * T_ + t0 + lane;
        float q = zq[lane][dd];
        float zv = z[base];
        out0[base] = q;
        float dv = zv - q;
        lacc += dv * dv;
    }
    #pragma unroll
    for (int off = 32; off >= 1; off >>= 1) lacc += __shfl_down(lacc, off);
    if (lane == 0) wsum[sub] = lacc;
    __syncthreads();
    if (tid == 0)
        lpart[(blockIdx.z * 16 + blockIdx.y) * 8 + blockIdx.x] =
            wsum[0] + wsum[1] + wsum[2] + wsum[3];
}

__global__ void vq_loss(const float* __restrict__ lpart, float* __restrict__ outL) {
    const int b = threadIdx.x;
    if (b >= B_) return;
    float s = 0.f;
    for (int q = 0; q < 128; q++) s += lpart[b * 128 + q];
    s /= (float)(D_ * T_);
    outL[b]      = s;
    outL[B_ + b] = s;
}

// ===========================================================================
extern "C" void kernel_launch(void* const* d_in, const int* in_sizes, int n_in,
                              void* d_out, int out_size, void* d_ws, size_t ws_size,
                              hipStream_t stream) {
    const float* z        = (const float*)d_in[0];   // [B, D, T]
    const float* codebook = (const float*)d_in[1];   // [V, CD]
    const float* cb_w     = (const float*)d_in[2];   // [D, CD]
    const float* cb_b     = (const float*)d_in[3];   // [D]

    float* out0 = (float*)d_out;
    float* outI = out0 + (size_t)B_*D_*T_;
    float* outL = outI + NR;

    char* p = (char*)d_ws;
    auto alloc = [&](size_t bytes) { char* r = p; p += (bytes + 255) & ~(size_t)255; return r; };
    unsigned short* w_hi = (unsigned short*)alloc((size_t)D_ * CD_ * 2);
    unsigned short* w_lo = (unsigned short*)alloc((size_t)D_ * CD_ * 2);
    unsigned short* p_hi = (unsigned short*)alloc((size_t)V_ * D_ * 2);
    unsigned short* p_lo = (unsigned short*)alloc((size_t)V_ * D_ * 2);
    unsigned short* e_hi = (unsigned short*)alloc((size_t)NR * D_ * 2);
    unsigned short* e_lo = (unsigned short*)alloc((size_t)NR * D_ * 2);
    float* ninv  = (float*)alloc((size_t)V_ * 4);
    float* pmax  = (float*)alloc((size_t)NR * VT2 * 4);
    int*   pidx  = (int*)  alloc((size_t)NR * VT2 * 4);
    int*   idxw  = (int*)  alloc((size_t)NR * 4);
    float* lpart = (float*)alloc((size_t)2048 * 4);
    unsigned short* c_hi = (unsigned short*)alloc((size_t)V_ * CD_ * 2);
    unsigned short* c_lo = (unsigned short*)alloc((size_t)V_ * CD_ * 2);
    // ~690 MB total; R10 proved >= 1.21 GB available

    vq_cvt8<<<512, 256, 0, stream>>>(cb_w, w_hi, w_lo, (size_t)D_ * CD_ / 8);
    vq_transpose_cvt<<<dim3(T_/64, D_/64, B_), 256, 0, stream>>>(z, e_hi, e_lo);
    vq_cvt8<<<2048, 256, 0, stream>>>(codebook, c_hi, c_lo, (size_t)V_ * CD_ / 8);

    vq_gemm1_t8<<<NTILE1, 512, 0, stream>>>(c_hi, c_lo, w_hi, w_lo,
                                            cb_b, p_hi, p_lo);
    vq_norms_pl<<<V_/4, 256, 0, stream>>>(p_hi, p_lo, ninv);
    vq_gemm2_t8<<<(NR/256) * VT2, 512, 0, stream>>>(e_hi, e_lo, p_hi, p_lo,
                                                    ninv, pmax, pidx);
    vq_argmerge<<<NR/256, 256, 0, stream>>>(pmax, pidx, idxw, outI, VT2);
    vq_gather_pl<<<dim3(T_/64, D_/64, B_), 256, 0, stream>>>(p_hi, p_lo, idxw, z,
                                                             out0, lpart);
    vq_loss<<<1, 64, 0, stream>>>(lpart, outL);
}